// Round 3
// baseline (28.828 us; speedup 1.0000x reference)
//
#include <hip/hip_runtime.h>
#include <hip/hip_bf16.h>

// MeanAggregator: out[b] = mean(features[neighbor_idx[b, :cnt[b]]]) if cnt>0
//                 else features[nodes[b]]
//
// 32 lanes per node (one float4 of the 128-float row each); block 256 = 8 nodes.
// All NUM_SAMPLE gather slots are unrolled; slot s loads ONLY if s < cnt
// (exec-masked, zero otherwise) so padded slots cost no memory traffic, while
// the real loads still issue back-to-back for latency overlap. cnt==0 seeds
// the accumulator with the node's own row instead.

#define B_NODES 50000
#define NUM_SAMPLE 10
#define D_FEAT 128
#define VEC_PER_ROW (D_FEAT / 4)   // 32 float4 per row

__global__ __launch_bounds__(256) void mean_agg_kernel(
    const int* __restrict__ nodes,
    const int* __restrict__ neighbor_idx,
    const int* __restrict__ neighbor_count,
    const float4* __restrict__ features4,   // [N_NODES * 32]
    float4* __restrict__ out4)              // [B * 32]
{
    const int node = blockIdx.x * 8 + (threadIdx.x >> 5);
    const int lane = threadIdx.x & 31;
    if (node >= B_NODES) return;

    const int cnt = neighbor_count[node];
    const int own = nodes[node];

    // 10 indices as 5x int2 (node*40 bytes is always 8B-aligned).
    const int2* nb2 = (const int2*)(neighbor_idx + node * NUM_SAMPLE);
    const int2 q0 = nb2[0], q1 = nb2[1], q2 = nb2[2], q3 = nb2[3], q4 = nb2[4];
    const int idx[NUM_SAMPLE] = {q0.x, q0.y, q1.x, q1.y, q2.x, q2.y, q3.x, q3.y, q4.x, q4.y};

    // Issue only the real gathers, back-to-back; padded slots stay zero.
    float4 v[NUM_SAMPLE];
    #pragma unroll
    for (int s = 0; s < NUM_SAMPLE; ++s) {
        v[s] = make_float4(0.f, 0.f, 0.f, 0.f);
        if (s < cnt) v[s] = features4[idx[s] * VEC_PER_ROW + lane];
    }

    // Empty neighbor list -> seed with own feature row (weight 1, denom 1).
    float4 acc = make_float4(0.f, 0.f, 0.f, 0.f);
    if (cnt == 0) acc = features4[own * VEC_PER_ROW + lane];

    #pragma unroll
    for (int s = 0; s < NUM_SAMPLE; ++s) {
        acc.x += v[s].x;
        acc.y += v[s].y;
        acc.z += v[s].z;
        acc.w += v[s].w;
    }

    const float inv = 1.0f / (float)((cnt > 1) ? cnt : 1);
    acc.x *= inv; acc.y *= inv; acc.z *= inv; acc.w *= inv;
    out4[node * VEC_PER_ROW + lane] = acc;
}

extern "C" void kernel_launch(void* const* d_in, const int* in_sizes, int n_in,
                              void* d_out, int out_size, void* d_ws, size_t ws_size,
                              hipStream_t stream) {
    const int*    nodes          = (const int*)d_in[0];
    const int*    neighbor_idx   = (const int*)d_in[1];
    const int*    neighbor_count = (const int*)d_in[2];
    const float4* features4      = (const float4*)d_in[3];
    float4*       out4           = (float4*)d_out;

    const int nodes_per_block = 8;            // 256 threads / 32 lanes-per-node
    const int grid = (B_NODES + nodes_per_block - 1) / nodes_per_block;
    mean_agg_kernel<<<grid, 256, 0, stream>>>(nodes, neighbor_idx, neighbor_count,
                                              features4, out4);
}

// Round 5
// 26.598 us; speedup vs baseline: 1.0839x; 1.0839x over previous
//
#include <hip/hip_runtime.h>
#include <hip/hip_bf16.h>

// MeanAggregator: out[b] = mean(features[neighbor_idx[b, :cnt[b]]]) if cnt>0
//                 else features[nodes[b]]
//
// 32 lanes per node-row (one f32x4 of the 128-float row each).
// Each 32-lane group handles TWO nodes: all 20 gathers issue back-to-back
// (predicated ADDRESS, not exec mask -- pads re-read the base row = L1 hit,
// branchless) before any accumulate, doubling per-wave MLP.
// Block 256 threads = 16 nodes. Output stored nontemporal (write-once).

#define B_NODES 50000
#define NUM_SAMPLE 10
#define D_FEAT 128
#define VEC_PER_ROW (D_FEAT / 4)   // 32 f32x4 per row
#define NODES_PER_BLOCK 16         // 8 groups x 2 nodes

typedef float f32x4 __attribute__((ext_vector_type(4)));

__global__ __launch_bounds__(256) void mean_agg_kernel(
    const int* __restrict__ nodes,
    const int* __restrict__ neighbor_idx,
    const int* __restrict__ neighbor_count,
    const f32x4* __restrict__ features4,   // [N_NODES * 32]
    f32x4* __restrict__ out4)              // [B * 32]
{
    const int grp  = threadIdx.x >> 5;          // 0..7
    const int lane = threadIdx.x & 31;
    const int nA = blockIdx.x * NODES_PER_BLOCK + grp;        // first node
    const int nB = nA + 8;                                    // second node
    // B_NODES = 50000 = 3125 * 16, so nA/nB are always in range.

    const int cntA = neighbor_count[nA];
    const int cntB = neighbor_count[nB];
    const int ownA = nodes[nA];
    const int ownB = nodes[nB];

    const int2* a2 = (const int2*)(neighbor_idx + nA * NUM_SAMPLE);
    const int2* b2 = (const int2*)(neighbor_idx + nB * NUM_SAMPLE);
    const int2 a0 = a2[0], a1 = a2[1], a2_ = a2[2], a3 = a2[3], a4 = a2[4];
    const int2 b0 = b2[0], b1 = b2[1], b2_ = b2[2], b3 = b2[3], b4 = b2[4];
    const int idxA[NUM_SAMPLE] = {a0.x, a0.y, a1.x, a1.y, a2_.x, a2_.y, a3.x, a3.y, a4.x, a4.y};
    const int idxB[NUM_SAMPLE] = {b0.x, b0.y, b1.x, b1.y, b2_.x, b2_.y, b3.x, b3.y, b4.x, b4.y};

    // Padded/empty slots re-read the base row (hot in L1 after slot 0).
    const int baseA = (cntA == 0) ? ownA : idxA[0];
    const int baseB = (cntB == 0) ? ownB : idxB[0];

    // Issue all 20 gathers back-to-back: maximal per-wave MLP.
    f32x4 vA[NUM_SAMPLE], vB[NUM_SAMPLE];
    #pragma unroll
    for (int s = 0; s < NUM_SAMPLE; ++s) {
        const int eA = (s < cntA) ? idxA[s] : baseA;
        vA[s] = features4[eA * VEC_PER_ROW + lane];
    }
    #pragma unroll
    for (int s = 0; s < NUM_SAMPLE; ++s) {
        const int eB = (s < cntB) ? idxB[s] : baseB;
        vB[s] = features4[eB * VEC_PER_ROW + lane];
    }

    // Slot 0 always has weight 1 (idx[0] if cnt>0, own row if cnt==0).
    f32x4 accA = vA[0];
    #pragma unroll
    for (int s = 1; s < NUM_SAMPLE; ++s) {
        const float w = (s < cntA) ? 1.0f : 0.0f;
        accA += w * vA[s];
    }
    accA *= 1.0f / (float)((cntA > 1) ? cntA : 1);
    __builtin_nontemporal_store(accA, &out4[nA * VEC_PER_ROW + lane]);

    f32x4 accB = vB[0];
    #pragma unroll
    for (int s = 1; s < NUM_SAMPLE; ++s) {
        const float w = (s < cntB) ? 1.0f : 0.0f;
        accB += w * vB[s];
    }
    accB *= 1.0f / (float)((cntB > 1) ? cntB : 1);
    __builtin_nontemporal_store(accB, &out4[nB * VEC_PER_ROW + lane]);
}

extern "C" void kernel_launch(void* const* d_in, const int* in_sizes, int n_in,
                              void* d_out, int out_size, void* d_ws, size_t ws_size,
                              hipStream_t stream) {
    const int*   nodes          = (const int*)d_in[0];
    const int*   neighbor_idx   = (const int*)d_in[1];
    const int*   neighbor_count = (const int*)d_in[2];
    const f32x4* features4      = (const f32x4*)d_in[3];
    f32x4*       out4           = (f32x4*)d_out;

    const int grid = (B_NODES + NODES_PER_BLOCK - 1) / NODES_PER_BLOCK;  // 3125
    mean_agg_kernel<<<grid, 256, 0, stream>>>(nodes, neighbor_idx, neighbor_count,
                                              features4, out4);
}